// Round 1
// baseline (688.760 us; speedup 1.0000x reference)
//
#include <hip/hip_runtime.h>
#include <hip/hip_bf16.h>

#define NN 50000
#define NE 800000
#define DD 128
#define KSEL 25000

__device__ __forceinline__ float sigmoidf(float x){ return 1.f/(1.f+__expf(-x)); }

// ---------------- degree ----------------
__global__ void k_deg(const int* __restrict__ dst, int* __restrict__ deg){
  int e = blockIdx.x*256+threadIdx.x;
  if(e<NE) atomicAdd(&deg[dst[e]],1);
}

// ---------------- exclusive scan over degrees (single block, wave scans) ----
__global__ __launch_bounds__(1024) void k_scan(const int* __restrict__ deg,
    int* __restrict__ row_start, int* __restrict__ cursor, float* __restrict__ inv_sq){
  __shared__ int wsum[16];
  __shared__ int wpre[16];
  __shared__ int base_sh;
  int tid=threadIdx.x, lane=tid&63, w=tid>>6;
  if(tid==0) base_sh=0;
  __syncthreads();
  for(int start=0; start<NN; start+=1024){
    int i=start+tid;
    int v=(i<NN)?deg[i]:0;
    int x=v;
    #pragma unroll
    for(int off=1; off<64; off<<=1){
      int y=__shfl_up(x,off,64);
      if(lane>=off) x+=y;
    }
    if(lane==63) wsum[w]=x;
    __syncthreads();
    if(w==0){
      int s=(lane<16)?wsum[lane]:0;
      #pragma unroll
      for(int off=1;off<16;off<<=1){
        int y=__shfl_up(s,off,64);
        if(lane>=off) s+=y;
      }
      if(lane<16) wpre[lane]=s;
    }
    __syncthreads();
    int base=base_sh;
    int incl=x+((w>0)?wpre[w-1]:0);
    if(i<NN){
      int excl=base+incl-v;
      row_start[i]=excl;
      cursor[i]=excl;
      inv_sq[i]=1.f/sqrtf((float)(v+1));   // + self loop, always >=1
    }
    __syncthreads();
    if(tid==1023) base_sh=base+incl;
    __syncthreads();
  }
  if(tid==0) row_start[NN]=base_sh;
}

// ---------------- CSR scatter ----------------
__global__ void k_csr(const int* __restrict__ src, const int* __restrict__ dst,
    int* __restrict__ cursor, int* __restrict__ csr_src){
  int e=blockIdx.x*256+threadIdx.x;
  if(e<NE){
    int d=dst[e];
    int p=atomicAdd(&cursor[d],1);
    csr_src[p]=src[e];
  }
}

// ---------------- 128x128 transpose (for Wbil^T) ----------------
__global__ void k_transpose(const float* __restrict__ W, float* __restrict__ Wt){
  int idx=blockIdx.x*256+threadIdx.x;
  if(idx<DD*DD){
    int k=idx>>7, c=idx&127;
    Wt[idx]=W[c*DD+k];
  }
}

// ---------------- fp32 GEMM: out[N,128] = actIn(A)[N,128] @ W[128,128] (+bias, actOut) ----
__global__ __launch_bounds__(256) void k_gemm(const float* __restrict__ A,
    const float* __restrict__ W, const float* __restrict__ bias,
    float* __restrict__ out, int act, const float* __restrict__ aparam, int in_sigmoid){
  __shared__ float Al[32][DD];            // 16 KB
  int tid=threadIdx.x;
  int row0=blockIdx.x*32;
  const float4* A4=(const float4*)(A+(size_t)row0*DD);
  float4* Al4=(float4*)&Al[0][0];
  #pragma unroll
  for(int i=0;i<4;i++){
    int idx=i*256+tid;
    int r=idx>>5;                          // 32 float4 per row
    float4 v=make_float4(0.f,0.f,0.f,0.f);
    if(row0+r<NN) v=A4[idx];
    if(in_sigmoid){ v.x=sigmoidf(v.x); v.y=sigmoidf(v.y); v.z=sigmoidf(v.z); v.w=sigmoidf(v.w); }
    Al4[idx]=v;
  }
  __syncthreads();
  int tx=tid&31, ty=tid>>5;
  float acc[4][4];
  #pragma unroll
  for(int i=0;i<4;i++){
    #pragma unroll
    for(int j=0;j<4;j++) acc[i][j]=0.f;
  }
  #pragma unroll 8
  for(int k=0;k<DD;k++){
    float4 wv=*(const float4*)&W[k*DD+tx*4];
    float a0=Al[ty*4+0][k], a1=Al[ty*4+1][k], a2=Al[ty*4+2][k], a3=Al[ty*4+3][k];
    acc[0][0]+=a0*wv.x; acc[0][1]+=a0*wv.y; acc[0][2]+=a0*wv.z; acc[0][3]+=a0*wv.w;
    acc[1][0]+=a1*wv.x; acc[1][1]+=a1*wv.y; acc[1][2]+=a1*wv.z; acc[1][3]+=a1*wv.w;
    acc[2][0]+=a2*wv.x; acc[2][1]+=a2*wv.y; acc[2][2]+=a2*wv.z; acc[2][3]+=a2*wv.w;
    acc[3][0]+=a3*wv.x; acc[3][1]+=a3*wv.y; acc[3][2]+=a3*wv.z; acc[3][3]+=a3*wv.w;
  }
  float4 bv=make_float4(0.f,0.f,0.f,0.f);
  if(bias) bv=*(const float4*)&bias[tx*4];
  float ap=(act==1)?aparam[0]:0.f;
  #pragma unroll
  for(int i=0;i<4;i++){
    int r=row0+ty*4+i;
    if(r<NN){
      float4 o;
      o.x=acc[i][0]+bv.x; o.y=acc[i][1]+bv.y; o.z=acc[i][2]+bv.z; o.w=acc[i][3]+bv.w;
      if(act==1){
        o.x=o.x>=0.f?o.x:ap*o.x; o.y=o.y>=0.f?o.y:ap*o.y;
        o.z=o.z>=0.f?o.z:ap*o.z; o.w=o.w>=0.f?o.w:ap*o.w;
      }
      *(float4*)&out[(size_t)r*DD+tx*4]=o;
    }
  }
}

// ---------------- GCN aggregation (CSR, one wave per node) ----------------
// mode 0: out = agg + bias                       (embed)
// mode 1: out = sel ? (agg+bias)*score : 0       (fine)
// mode 2: out = agg + bias + addbuf              (final + embed residual)
__global__ __launch_bounds__(256) void k_agg(const float* __restrict__ xw,
    const int* __restrict__ row_start, const int* __restrict__ csr_src,
    const float* __restrict__ inv_sq, const float* __restrict__ bias,
    float* __restrict__ out, int mode, const float* __restrict__ score,
    const unsigned char* __restrict__ sel, const float* __restrict__ addbuf){
  int node=blockIdx.x*4+(threadIdx.x>>6);
  if(node>=NN) return;
  int lane=threadIdx.x&63;
  int rs=row_start[node], re=row_start[node+1];
  float wd=inv_sq[node];
  float ax=0.f, ay=0.f;
  int j=rs;
  for(; j+1<re; j+=2){
    int s0=csr_src[j], s1=csr_src[j+1];
    float w0=inv_sq[s0], w1=inv_sq[s1];
    float2 v0=*(const float2*)&xw[(size_t)s0*DD+lane*2];
    float2 v1=*(const float2*)&xw[(size_t)s1*DD+lane*2];
    ax+=v0.x*w0+v1.x*w1; ay+=v0.y*w0+v1.y*w1;
  }
  if(j<re){
    int s0=csr_src[j];
    float w0=inv_sq[s0];
    float2 v0=*(const float2*)&xw[(size_t)s0*DD+lane*2];
    ax+=v0.x*w0; ay+=v0.y*w0;
  }
  float2 vd=*(const float2*)&xw[(size_t)node*DD+lane*2];
  ax=(ax+vd.x*wd)*wd;
  ay=(ay+vd.y*wd)*wd;
  float2 bv=*(const float2*)&bias[lane*2];
  float rx=ax+bv.x, ry=ay+bv.y;
  if(mode==1){
    if(sel[node]){ float sc=score[node]; rx*=sc; ry*=sc; }
    else { rx=0.f; ry=0.f; }
  } else if(mode==2){
    float2 ad=*(const float2*)&addbuf[(size_t)node*DD+lane*2];
    rx+=ad.x; ry+=ad.y;
  }
  float2 o; o.x=rx; o.y=ry;
  *(float2*)&out[(size_t)node*DD+lane*2]=o;
}

// ---------------- bilinear score: score[n] = sigmoid(dot(h_pos[n],T[n]) + bbil) ----
__global__ __launch_bounds__(256) void k_score(const float* __restrict__ hp,
    const float* __restrict__ T, const float* __restrict__ bbil, float* __restrict__ score){
  int node=blockIdx.x*4+(threadIdx.x>>6);
  if(node>=NN) return;
  int lane=threadIdx.x&63;
  float2 a=*(const float2*)&hp[(size_t)node*DD+lane*2];
  float2 t=*(const float2*)&T[(size_t)node*DD+lane*2];
  float p=a.x*t.x+a.y*t.y;
  #pragma unroll
  for(int off=32; off; off>>=1) p+=__shfl_xor(p,off,64);
  if(lane==0) score[node]=sigmoidf(p+bbil[0]);
}

// ---------------- radix-select: histograms ----------------
__global__ void k_hist(const float* __restrict__ score, int* __restrict__ hist,
                       int phase, const int* __restrict__ ctrl){
  int i=blockIdx.x*256+threadIdx.x;
  if(i>=NN) return;
  unsigned b=__float_as_uint(score[i]);   // scores in (0,1): positive -> uint order == value order
  if(phase==0) atomicAdd(&hist[b>>16],1);
  else if((b>>16)==(unsigned)ctrl[0]) atomicAdd(&hist[b&0xffffu],1);
}

// find bucket where descending cumulative count crosses KSEL
__global__ __launch_bounds__(1024) void k_findb(const int* __restrict__ hist,
                                                int* __restrict__ ctrl, int phase){
  __shared__ int gsum[1024];
  int tid=threadIdx.x;
  int s=0;
  const int4* h4=(const int4*)hist;
  #pragma unroll
  for(int i=0;i<16;i++){ int4 v=h4[tid*16+i]; s+=v.x+v.y+v.z+v.w; }
  int x=s;
  gsum[tid]=x; __syncthreads();
  for(int off=1;off<1024;off<<=1){
    int y=(tid+off<1024)?gsum[tid+off]:0;
    __syncthreads();
    x+=y; gsum[tid]=x; __syncthreads();
  }
  // gsum[t] = sum over groups >= t
  int base=(phase==1)?ctrl[1]:0;
  int above=base+((tid<1023)?gsum[tid+1]:0);
  int incl=base+gsum[tid];
  if(above<KSEL && incl>=KSEL){
    int c=above;
    int B=-1;
    for(int b=63;b>=0;b--){
      int hb=hist[tid*64+b];
      if(c+hb>=KSEL){ B=tid*64+b; break; }
      c+=hb;
    }
    if(phase==0){ ctrl[0]=B; ctrl[1]=c; }
    else{
      ctrl[4]=(int)(((unsigned)ctrl[0]<<16)|(unsigned)B);
      ctrl[5]=KSEL-c;                     // ties needed
    }
  }
}

__global__ void k_sel(const float* __restrict__ score, int* __restrict__ ctrl,
                      int* __restrict__ tie_list, unsigned char* __restrict__ sel){
  int i=blockIdx.x*256+threadIdx.x;
  if(i>=NN) return;
  unsigned b=__float_as_uint(score[i]);
  unsigned thr=(unsigned)ctrl[4];
  if(b>thr){ sel[i]=1; }
  else if(b==thr){
    sel[i]=0;
    int p=atomicAdd(&ctrl[6],1);
    if(p<4096) tie_list[p]=i;
  } else sel[i]=0;
}

// stable-tie resolution: among equal-to-threshold scores pick smallest indices
__global__ __launch_bounds__(256) void k_tie(const int* __restrict__ ctrl,
    const int* __restrict__ tie_list, unsigned char* __restrict__ sel){
  int m=ctrl[6]; if(m>4096) m=4096;
  int needed=ctrl[5];
  for(int t=threadIdx.x; t<m; t+=blockDim.x){
    int idx=tie_list[t];
    int rank=0;
    for(int j=0;j<m;j++) rank+=(tie_list[j]<idx)?1:0;
    if(rank<needed) sel[idx]=1;
  }
}

// ============================================================================
extern "C" void kernel_launch(void* const* d_in, const int* in_sizes, int n_in,
                              void* d_out, int out_size, void* d_ws, size_t ws_size,
                              hipStream_t stream){
  const float* feat   =(const float*)d_in[0];
  // d_in[1] = h_neg : dead code in reference
  const int*   ei     =(const int*)  d_in[2];
  const int*   src    = ei;
  const int*   dst    = ei + NE;
  const float* Wd     =(const float*)d_in[3];
  const float* bd     =(const float*)d_in[4];
  const float* prelu_a=(const float*)d_in[5];
  const float* Wbil   =(const float*)d_in[6];
  const float* bbil   =(const float*)d_in[7];
  const float* Wg1    =(const float*)d_in[8];
  const float* bg1    =(const float*)d_in[9];
  const float* Wg2    =(const float*)d_in[10];
  const float* bg2    =(const float*)d_in[11];
  const float* Wg3    =(const float*)d_in[12];
  const float* bg3    =(const float*)d_in[13];
  float* out=(float*)d_out;

  char* p=(char*)d_ws;
  auto alloc=[&](size_t bytes)->void*{ void* r=(void*)p; p+=((bytes+255)/256)*256; return r; };
  float* h_pos   =(float*)alloc((size_t)NN*DD*4);
  float* embed   =(float*)alloc((size_t)NN*DD*4);
  float* xw      =(float*)alloc((size_t)NN*DD*4);   // reused: xw1, T, xw2, xw3
  float* score   =(float*)alloc((size_t)NN*4);
  float* inv_sq  =(float*)alloc((size_t)NN*4);
  float* WbT     =(float*)alloc((size_t)DD*DD*4);
  int*   deg     =(int*)  alloc((size_t)NN*4);
  int*   row_st  =(int*)  alloc((size_t)(NN+1)*4);
  int*   cursor  =(int*)  alloc((size_t)NN*4);
  int*   csr_src =(int*)  alloc((size_t)NE*4);
  int*   hist    =(int*)  alloc(65536*4);
  int*   ctrl    =(int*)  alloc(64);
  int*   tie_list=(int*)  alloc(4096*4);
  unsigned char* sel=(unsigned char*)alloc(NN);
  // fine buffer lives in d_out (fully overwritten at the end)
  float* fine = out;

  const int EB=(NE+255)/256;     // 3125
  const int NB=(NN+255)/256;     // 196
  const int GB=(NN+31)/32;       // 1563 gemm blocks
  const int AB=(NN+3)/4;         // 12500 agg/score blocks

  hipMemsetAsync(deg, 0, (size_t)NN*4, stream);
  hipMemsetAsync(ctrl, 0, 64, stream);

  // graph structure (feature-independent)
  k_deg<<<EB,256,0,stream>>>(dst, deg);
  k_scan<<<1,1024,0,stream>>>(deg, row_st, cursor, inv_sq);
  k_csr<<<EB,256,0,stream>>>(src, dst, cursor, csr_src);
  k_transpose<<<64,256,0,stream>>>(Wbil, WbT);

  // h_pos = prelu(feat @ Wd + bd)
  k_gemm<<<GB,256,0,stream>>>(feat, Wd, bd, h_pos, 1, prelu_a, 0);
  // embed = gcn1(h_pos)
  k_gemm<<<GB,256,0,stream>>>(h_pos, Wg1, nullptr, xw, 0, nullptr, 0);
  k_agg<<<AB,256,0,stream>>>(xw, row_st, csr_src, inv_sq, bg1, embed, 0, nullptr, nullptr, nullptr);
  // T = sigmoid(embed) @ Wbil^T ; score = sigmoid(rowdot(h_pos,T)+bbil)
  k_gemm<<<GB,256,0,stream>>>(embed, WbT, nullptr, xw, 0, nullptr, 1);
  k_score<<<AB,256,0,stream>>>(h_pos, xw, bbil, score);
  // top-k threshold via 2-pass radix select on float bits
  hipMemsetAsync(hist, 0, 65536*4, stream);
  k_hist<<<NB,256,0,stream>>>(score, hist, 0, ctrl);
  k_findb<<<1,1024,0,stream>>>(hist, ctrl, 0);
  hipMemsetAsync(hist, 0, 65536*4, stream);
  k_hist<<<NB,256,0,stream>>>(score, hist, 1, ctrl);
  k_findb<<<1,1024,0,stream>>>(hist, ctrl, 1);
  k_sel<<<NB,256,0,stream>>>(score, ctrl, tie_list, sel);
  k_tie<<<1,256,0,stream>>>(ctrl, tie_list, sel);
  // fine = sel ? gcn2(embed)*score : 0      (written into d_out as scratch)
  k_gemm<<<GB,256,0,stream>>>(embed, Wg2, nullptr, xw, 0, nullptr, 0);
  k_agg<<<AB,256,0,stream>>>(xw, row_st, csr_src, inv_sq, bg2, fine, 1, score, sel, nullptr);
  // out = gcn3(fine) + embed
  k_gemm<<<GB,256,0,stream>>>(fine, Wg3, nullptr, xw, 0, nullptr, 0);
  k_agg<<<AB,256,0,stream>>>(xw, row_st, csr_src, inv_sq, bg3, out, 2, nullptr, nullptr, embed);
}

// Round 2
// 625.376 us; speedup vs baseline: 1.1014x; 1.1014x over previous
//
#include <hip/hip_runtime.h>
#include <hip/hip_bf16.h>

#define NN 50000
#define NE 800000
#define DD 128
#define KSEL 25000

typedef unsigned int uint32;
typedef unsigned short ushort16;

__device__ __forceinline__ float sigmoidf(float x){ return 1.f/(1.f+__expf(-x)); }

__device__ __forceinline__ unsigned short f2b(float f){
  union{float f; unsigned u;} v; v.f=f;
  unsigned r=(v.u + 0x7fffu + ((v.u>>16)&1u))>>16;
  return (unsigned short)r;
}

// ---------------- degree ----------------
__global__ void k_deg(const int* __restrict__ dst, int* __restrict__ deg){
  int e = blockIdx.x*256+threadIdx.x;
  if(e<NE) atomicAdd(&deg[dst[e]],1);
}

// ---------------- exclusive scan over degrees (single block) ----------------
__global__ __launch_bounds__(1024) void k_scan(const int* __restrict__ deg,
    int* __restrict__ row_start, int* __restrict__ cursor, float* __restrict__ inv_sq){
  __shared__ int wsum[16];
  __shared__ int wpre[16];
  __shared__ int base_sh;
  int tid=threadIdx.x, lane=tid&63, w=tid>>6;
  if(tid==0) base_sh=0;
  __syncthreads();
  for(int start=0; start<NN; start+=1024){
    int i=start+tid;
    int v=(i<NN)?deg[i]:0;
    int x=v;
    #pragma unroll
    for(int off=1; off<64; off<<=1){
      int y=__shfl_up(x,off,64);
      if(lane>=off) x+=y;
    }
    if(lane==63) wsum[w]=x;
    __syncthreads();
    if(w==0){
      int s=(lane<16)?wsum[lane]:0;
      #pragma unroll
      for(int off=1;off<16;off<<=1){
        int y=__shfl_up(s,off,64);
        if(lane>=off) s+=y;
      }
      if(lane<16) wpre[lane]=s;
    }
    __syncthreads();
    int base=base_sh;
    int incl=x+((w>0)?wpre[w-1]:0);
    if(i<NN){
      int excl=base+incl-v;
      row_start[i]=excl;
      cursor[i]=excl;
      inv_sq[i]=1.f/sqrtf((float)(v+1));
    }
    __syncthreads();
    if(tid==1023) base_sh=base+incl;
    __syncthreads();
  }
  if(tid==0) row_start[NN]=base_sh;
}

// ---------------- CSR scatter ----------------
__global__ void k_csr(const int* __restrict__ src, const int* __restrict__ dst,
    int* __restrict__ cursor, int* __restrict__ csr_src){
  int e=blockIdx.x*256+threadIdx.x;
  if(e<NE){
    int d=dst[e];
    int p=atomicAdd(&cursor[d],1);
    csr_src[p]=src[e];
  }
}

// ---------------- 128x128 transpose (Wbil^T) ----------------
__global__ void k_transpose(const float* __restrict__ W, float* __restrict__ Wt){
  int idx=blockIdx.x*256+threadIdx.x;
  if(idx<DD*DD){
    int k=idx>>7, c=idx&127;
    Wt[idx]=W[c*DD+k];
  }
}

// ---------------- fp32 GEMM, 64 rows/block, 8x4 acc/thread --------------
// IN_SIG: sigmoid(A) on load; ACT: prelu epilogue; OUT_BF16: bf16 output;
// FUSE_SCORE: no store, score[r]=sigmoid(dot(acc_row, hp[r])+bbil)
template<int IN_SIG,int ACT,int OUT_BF16,int FUSE_SCORE>
__global__ __launch_bounds__(256) void k_gemm64(const float* __restrict__ A,
    const float* __restrict__ W, const float* __restrict__ bias,
    float* __restrict__ outf, ushort16* __restrict__ outb,
    const float* __restrict__ aparam, const float* __restrict__ hp,
    const float* __restrict__ bbil, float* __restrict__ score){
  __shared__ float Al[64][DD];            // 32 KB
  int tid=threadIdx.x;
  int row0=blockIdx.x*64;
  const float4* A4=(const float4*)(A+(size_t)row0*DD);
  float4* Al4=(float4*)&Al[0][0];
  #pragma unroll
  for(int i=0;i<8;i++){
    int idx=i*256+tid;                    // 2048 float4 = 64 rows
    int r=idx>>5;
    float4 v=make_float4(0.f,0.f,0.f,0.f);
    if(row0+r<NN) v=A4[idx];
    if(IN_SIG){ v.x=sigmoidf(v.x); v.y=sigmoidf(v.y); v.z=sigmoidf(v.z); v.w=sigmoidf(v.w); }
    Al4[idx]=v;
  }
  __syncthreads();
  int tx=tid&31, ty=tid>>5;
  float acc[8][4];
  #pragma unroll
  for(int i=0;i<8;i++){
    #pragma unroll
    for(int j=0;j<4;j++) acc[i][j]=0.f;
  }
  const float4* Wp=(const float4*)W;
  #pragma unroll 2
  for(int k=0;k<DD;k+=4){
    float4 w0=Wp[(k+0)*32+tx];
    float4 w1=Wp[(k+1)*32+tx];
    float4 w2=Wp[(k+2)*32+tx];
    float4 w3=Wp[(k+3)*32+tx];
    #pragma unroll
    for(int i=0;i<8;i++){
      float4 a=*(const float4*)&Al[ty*8+i][k];
      acc[i][0]+=a.x*w0.x+a.y*w1.x+a.z*w2.x+a.w*w3.x;
      acc[i][1]+=a.x*w0.y+a.y*w1.y+a.z*w2.y+a.w*w3.y;
      acc[i][2]+=a.x*w0.z+a.y*w1.z+a.z*w2.z+a.w*w3.z;
      acc[i][3]+=a.x*w0.w+a.y*w1.w+a.z*w2.w+a.w*w3.w;
    }
  }
  if(FUSE_SCORE){
    float bb=bbil[0];
    #pragma unroll
    for(int i=0;i<8;i++){
      int r=row0+ty*8+i;
      float p=0.f;
      if(r<NN){
        float4 h=*(const float4*)&hp[(size_t)r*DD+tx*4];
        p=acc[i][0]*h.x+acc[i][1]*h.y+acc[i][2]*h.z+acc[i][3]*h.w;
      }
      #pragma unroll
      for(int off=16;off;off>>=1) p+=__shfl_xor(p,off,64);   // reduce within 32-lane half
      if(tx==0 && r<NN) score[r]=sigmoidf(p+bb);
    }
    return;
  }
  float4 bv=make_float4(0.f,0.f,0.f,0.f);
  if(bias) bv=*(const float4*)&bias[tx*4];
  float ap=ACT?aparam[0]:0.f;
  #pragma unroll
  for(int i=0;i<8;i++){
    int r=row0+ty*8+i;
    if(r<NN){
      float4 o;
      o.x=acc[i][0]+bv.x; o.y=acc[i][1]+bv.y; o.z=acc[i][2]+bv.z; o.w=acc[i][3]+bv.w;
      if(ACT){
        o.x=o.x>=0.f?o.x:ap*o.x; o.y=o.y>=0.f?o.y:ap*o.y;
        o.z=o.z>=0.f?o.z:ap*o.z; o.w=o.w>=0.f?o.w:ap*o.w;
      }
      if(OUT_BF16){
        uint32 p0=((uint32)f2b(o.y)<<16)|f2b(o.x);
        uint32 p1=((uint32)f2b(o.w)<<16)|f2b(o.z);
        uint2 pk; pk.x=p0; pk.y=p1;
        *(uint2*)&outb[(size_t)r*DD+tx*4]=pk;
      } else {
        *(float4*)&outf[(size_t)r*DD+tx*4]=o;
      }
    }
  }
}

// ---------------- fp32 GCN aggregation (embed) ---------------------------
__global__ __launch_bounds__(256) void k_agg_f32(const float* __restrict__ xw,
    const int* __restrict__ row_start, const int* __restrict__ csr,
    const float* __restrict__ inv, const float* __restrict__ bias,
    float* __restrict__ outp){
  int node=blockIdx.x*4+(threadIdx.x>>6);
  if(node>=NN) return;
  int lane=threadIdx.x&63;
  int rs=row_start[node], re=row_start[node+1];
  float ax=0.f, ay=0.f;
  int j=rs;
  for(; j+3<re; j+=4){
    int s0=csr[j],s1=csr[j+1],s2=csr[j+2],s3=csr[j+3];
    float w0=inv[s0],w1=inv[s1],w2=inv[s2],w3=inv[s3];
    float2 v0=*(const float2*)&xw[(size_t)s0*DD+lane*2];
    float2 v1=*(const float2*)&xw[(size_t)s1*DD+lane*2];
    float2 v2=*(const float2*)&xw[(size_t)s2*DD+lane*2];
    float2 v3=*(const float2*)&xw[(size_t)s3*DD+lane*2];
    ax+=v0.x*w0+v1.x*w1+v2.x*w2+v3.x*w3;
    ay+=v0.y*w0+v1.y*w1+v2.y*w2+v3.y*w3;
  }
  for(; j<re; j++){
    int s=csr[j]; float w=inv[s];
    float2 v=*(const float2*)&xw[(size_t)s*DD+lane*2];
    ax+=v.x*w; ay+=v.y*w;
  }
  float wd=inv[node];
  float2 vd=*(const float2*)&xw[(size_t)node*DD+lane*2];
  ax=(ax+vd.x*wd)*wd; ay=(ay+vd.y*wd)*wd;
  float2 bv=*(const float2*)&bias[lane*2];
  float2 o; o.x=ax+bv.x; o.y=ay+bv.y;
  *(float2*)&outp[(size_t)node*DD+lane*2]=o;
}

// ---------------- bf16 GCN aggregation -----------------------------------
// MODE 1: out = sel[node] ? (agg+bias)*score : 0        (fine)
// MODE 2: out = agg(skip !sel[s] rows, exactly 0) + bias + addbuf
template<int MODE>
__global__ __launch_bounds__(256) void k_agg_b16(const uint32* __restrict__ xwb,
    const int* __restrict__ row_start, const int* __restrict__ csr,
    const float* __restrict__ inv, const float* __restrict__ bias,
    float* __restrict__ outp, const float* __restrict__ score,
    const unsigned char* __restrict__ sel, const float* __restrict__ addbuf){
  int node=blockIdx.x*4+(threadIdx.x>>6);
  if(node>=NN) return;
  int lane=threadIdx.x&63;
  if(MODE==1 && !sel[node]){
    float2 z; z.x=0.f; z.y=0.f;
    *(float2*)&outp[(size_t)node*DD+lane*2]=z;
    return;
  }
  int rs=row_start[node], re=row_start[node+1];
  float ax=0.f, ay=0.f;
  int j=rs;
  for(; j+3<re; j+=4){
    int s0=csr[j],s1=csr[j+1],s2=csr[j+2],s3=csr[j+3];
    if(MODE!=2 || sel[s0]){
      float w=inv[s0]; uint32 u=xwb[(size_t)s0*64+lane];
      ax+=__uint_as_float(u<<16)*w; ay+=__uint_as_float(u&0xffff0000u)*w;
    }
    if(MODE!=2 || sel[s1]){
      float w=inv[s1]; uint32 u=xwb[(size_t)s1*64+lane];
      ax+=__uint_as_float(u<<16)*w; ay+=__uint_as_float(u&0xffff0000u)*w;
    }
    if(MODE!=2 || sel[s2]){
      float w=inv[s2]; uint32 u=xwb[(size_t)s2*64+lane];
      ax+=__uint_as_float(u<<16)*w; ay+=__uint_as_float(u&0xffff0000u)*w;
    }
    if(MODE!=2 || sel[s3]){
      float w=inv[s3]; uint32 u=xwb[(size_t)s3*64+lane];
      ax+=__uint_as_float(u<<16)*w; ay+=__uint_as_float(u&0xffff0000u)*w;
    }
  }
  for(; j<re; j++){
    int s=csr[j];
    if(MODE!=2 || sel[s]){
      float w=inv[s]; uint32 u=xwb[(size_t)s*64+lane];
      ax+=__uint_as_float(u<<16)*w; ay+=__uint_as_float(u&0xffff0000u)*w;
    }
  }
  // self loop
  if(MODE!=2 || sel[node]){
    float wd=inv[node];
    uint32 u=xwb[(size_t)node*64+lane];
    ax+=__uint_as_float(u<<16)*wd; ay+=__uint_as_float(u&0xffff0000u)*wd;
  }
  float wn=inv[node];
  ax*=wn; ay*=wn;
  float2 bv=*(const float2*)&bias[lane*2];
  float rx=ax+bv.x, ry=ay+bv.y;
  if(MODE==1){
    float sc=score[node]; rx*=sc; ry*=sc;
  } else {
    float2 ad=*(const float2*)&addbuf[(size_t)node*DD+lane*2];
    rx+=ad.x; ry+=ad.y;
  }
  float2 o; o.x=rx; o.y=ry;
  *(float2*)&outp[(size_t)node*DD+lane*2]=o;
}

// ---------------- radix-select ----------------
__global__ void k_hist(const float* __restrict__ score, int* __restrict__ hist,
                       int phase, const int* __restrict__ ctrl){
  int i=blockIdx.x*256+threadIdx.x;
  if(i>=NN) return;
  unsigned b=__float_as_uint(score[i]);
  if(phase==0) atomicAdd(&hist[b>>16],1);
  else if((b>>16)==(unsigned)ctrl[0]) atomicAdd(&hist[b&0xffffu],1);
}

__global__ __launch_bounds__(1024) void k_findb(const int* __restrict__ hist,
                                                int* __restrict__ ctrl, int phase){
  __shared__ int gsum[1024];
  int tid=threadIdx.x;
  int s=0;
  const int4* h4=(const int4*)hist;
  #pragma unroll
  for(int i=0;i<16;i++){ int4 v=h4[tid*16+i]; s+=v.x+v.y+v.z+v.w; }
  int x=s;
  gsum[tid]=x; __syncthreads();
  for(int off=1;off<1024;off<<=1){
    int y=(tid+off<1024)?gsum[tid+off]:0;
    __syncthreads();
    x+=y; gsum[tid]=x; __syncthreads();
  }
  int base=(phase==1)?ctrl[1]:0;
  int above=base+((tid<1023)?gsum[tid+1]:0);
  int incl=base+gsum[tid];
  if(above<KSEL && incl>=KSEL){
    int c=above;
    int B=-1;
    for(int b=63;b>=0;b--){
      int hb=hist[tid*64+b];
      if(c+hb>=KSEL){ B=tid*64+b; break; }
      c+=hb;
    }
    if(phase==0){ ctrl[0]=B; ctrl[1]=c; }
    else{
      ctrl[4]=(int)(((unsigned)ctrl[0]<<16)|(unsigned)B);
      ctrl[5]=KSEL-c;
    }
  }
}

__global__ void k_sel(const float* __restrict__ score, int* __restrict__ ctrl,
                      int* __restrict__ tie_list, unsigned char* __restrict__ sel){
  int i=blockIdx.x*256+threadIdx.x;
  if(i>=NN) return;
  unsigned b=__float_as_uint(score[i]);
  unsigned thr=(unsigned)ctrl[4];
  if(b>thr){ sel[i]=1; }
  else if(b==thr){
    sel[i]=0;
    int p=atomicAdd(&ctrl[6],1);
    if(p<4096) tie_list[p]=i;
  } else sel[i]=0;
}

__global__ __launch_bounds__(256) void k_tie(const int* __restrict__ ctrl,
    const int* __restrict__ tie_list, unsigned char* __restrict__ sel){
  int m=ctrl[6]; if(m>4096) m=4096;
  int needed=ctrl[5];
  for(int t=threadIdx.x; t<m; t+=blockDim.x){
    int idx=tie_list[t];
    int rank=0;
    for(int j=0;j<m;j++) rank+=(tie_list[j]<idx)?1:0;
    if(rank<needed) sel[idx]=1;
  }
}

// ============================================================================
extern "C" void kernel_launch(void* const* d_in, const int* in_sizes, int n_in,
                              void* d_out, int out_size, void* d_ws, size_t ws_size,
                              hipStream_t stream){
  const float* feat   =(const float*)d_in[0];
  const int*   ei     =(const int*)  d_in[2];
  const int*   src    = ei;
  const int*   dst    = ei + NE;
  const float* Wd     =(const float*)d_in[3];
  const float* bd     =(const float*)d_in[4];
  const float* prelu_a=(const float*)d_in[5];
  const float* Wbil   =(const float*)d_in[6];
  const float* bbil   =(const float*)d_in[7];
  const float* Wg1    =(const float*)d_in[8];
  const float* bg1    =(const float*)d_in[9];
  const float* Wg2    =(const float*)d_in[10];
  const float* bg2    =(const float*)d_in[11];
  const float* Wg3    =(const float*)d_in[12];
  const float* bg3    =(const float*)d_in[13];
  float* out=(float*)d_out;

  char* p=(char*)d_ws;
  auto alloc=[&](size_t bytes)->void*{ void* r=(void*)p; p+=((bytes+255)/256)*256; return r; };
  float* h_pos   =(float*)alloc((size_t)NN*DD*4);
  float* embed   =(float*)alloc((size_t)NN*DD*4);
  float* xw      =(float*)alloc((size_t)NN*DD*4);   // fp32 xw1; later aliased as bf16 xw2/xw3
  float* score   =(float*)alloc((size_t)NN*4);
  float* inv_sq  =(float*)alloc((size_t)NN*4);
  float* WbT     =(float*)alloc((size_t)DD*DD*4);
  int*   deg     =(int*)  alloc((size_t)NN*4);
  int*   row_st  =(int*)  alloc((size_t)(NN+1)*4);
  int*   cursor  =(int*)  alloc((size_t)NN*4);
  int*   csr_src =(int*)  alloc((size_t)NE*4);
  int*   hist    =(int*)  alloc(65536*4);
  int*   ctrl    =(int*)  alloc(64);
  int*   tie_list=(int*)  alloc(4096*4);
  unsigned char* sel=(unsigned char*)alloc(NN);
  ushort16* xwb  =(ushort16*)xw;                    // bf16 alias (lifetimes disjoint)
  float* fine = out;                                // scratch in d_out (fully overwritten)

  const int EB=(NE+255)/256;
  const int NB=(NN+255)/256;
  const int GB=(NN+63)/64;       // 782
  const int AB=(NN+3)/4;         // 12500

  hipMemsetAsync(deg, 0, (size_t)NN*4, stream);
  hipMemsetAsync(ctrl, 0, 64, stream);

  k_deg<<<EB,256,0,stream>>>(dst, deg);
  k_scan<<<1,1024,0,stream>>>(deg, row_st, cursor, inv_sq);
  k_csr<<<EB,256,0,stream>>>(src, dst, cursor, csr_src);
  k_transpose<<<64,256,0,stream>>>(Wbil, WbT);

  // h_pos = prelu(feat @ Wd + bd)
  k_gemm64<0,1,0,0><<<GB,256,0,stream>>>(feat, Wd, bd, h_pos, nullptr, prelu_a, nullptr, nullptr, nullptr);
  // embed = gcn1(h_pos)
  k_gemm64<0,0,0,0><<<GB,256,0,stream>>>(h_pos, Wg1, nullptr, xw, nullptr, nullptr, nullptr, nullptr, nullptr);
  k_agg_f32<<<AB,256,0,stream>>>(xw, row_st, csr_src, inv_sq, bg1, embed);
  // score = sigmoid(rowdot(h_pos, sigmoid(embed)@Wbil^T) + bbil)   [fused]
  k_gemm64<1,0,0,1><<<GB,256,0,stream>>>(embed, WbT, nullptr, nullptr, nullptr, nullptr, h_pos, bbil, score);
  // top-k radix select
  hipMemsetAsync(hist, 0, 65536*4, stream);
  k_hist<<<NB,256,0,stream>>>(score, hist, 0, ctrl);
  k_findb<<<1,1024,0,stream>>>(hist, ctrl, 0);
  hipMemsetAsync(hist, 0, 65536*4, stream);
  k_hist<<<NB,256,0,stream>>>(score, hist, 1, ctrl);
  k_findb<<<1,1024,0,stream>>>(hist, ctrl, 1);
  k_sel<<<NB,256,0,stream>>>(score, ctrl, tie_list, sel);
  k_tie<<<1,256,0,stream>>>(ctrl, tie_list, sel);
  // fine = sel ? gcn2(embed)*score : 0   (bf16 xw2)
  k_gemm64<0,0,1,0><<<GB,256,0,stream>>>(embed, Wg2, nullptr, nullptr, xwb, nullptr, nullptr, nullptr, nullptr);
  k_agg_b16<1><<<AB,256,0,stream>>>((const uint32*)xwb, row_st, csr_src, inv_sq, bg2, fine, score, sel, nullptr);
  // out = gcn3(fine) + embed             (bf16 xw3, skip exact-zero rows)
  k_gemm64<0,0,1,0><<<GB,256,0,stream>>>(fine, Wg3, nullptr, nullptr, xwb, nullptr, nullptr, nullptr, nullptr);
  k_agg_b16<2><<<AB,256,0,stream>>>((const uint32*)xwb, row_st, csr_src, inv_sq, bg3, out, nullptr, sel, embed);
}

// Round 3
// 482.021 us; speedup vs baseline: 1.4289x; 1.2974x over previous
//
#include <hip/hip_runtime.h>
#include <hip/hip_bf16.h>

#define NN 50000
#define NE 800000
#define DD 128
#define KSEL 25000

typedef unsigned int uint32;
typedef unsigned short ushort16;

__device__ __forceinline__ float sigmoidf(float x){ return 1.f/(1.f+__expf(-x)); }

__device__ __forceinline__ unsigned short f2b(float f){
  union{float f; unsigned u;} v; v.f=f;
  unsigned r=(v.u + 0x7fffu + ((v.u>>16)&1u))>>16;
  return (unsigned short)r;
}

__device__ __forceinline__ void addbf2(float&lo,float&hi,uint32 u,float w){
  lo+=__uint_as_float(u<<16)*w;
  hi+=__uint_as_float(u&0xffff0000u)*w;
}

// ---------------- degree ----------------
__global__ void k_deg(const int* __restrict__ dst, int* __restrict__ deg){
  int e = blockIdx.x*256+threadIdx.x;
  if(e<NE) atomicAdd(&deg[dst[e]],1);
}

// ---------------- exclusive scan over degrees (single block) ----------------
__global__ __launch_bounds__(1024) void k_scan(const int* __restrict__ deg,
    int* __restrict__ row_start, int* __restrict__ cursor, float* __restrict__ inv_sq){
  __shared__ int wsum[16];
  __shared__ int wpre[16];
  __shared__ int base_sh;
  int tid=threadIdx.x, lane=tid&63, w=tid>>6;
  if(tid==0) base_sh=0;
  __syncthreads();
  for(int start=0; start<NN; start+=1024){
    int i=start+tid;
    int v=(i<NN)?deg[i]:0;
    int x=v;
    #pragma unroll
    for(int off=1; off<64; off<<=1){
      int y=__shfl_up(x,off,64);
      if(lane>=off) x+=y;
    }
    if(lane==63) wsum[w]=x;
    __syncthreads();
    if(w==0){
      int s=(lane<16)?wsum[lane]:0;
      #pragma unroll
      for(int off=1;off<16;off<<=1){
        int y=__shfl_up(s,off,64);
        if(lane>=off) s+=y;
      }
      if(lane<16) wpre[lane]=s;
    }
    __syncthreads();
    int base=base_sh;
    int incl=x+((w>0)?wpre[w-1]:0);
    if(i<NN){
      int excl=base+incl-v;
      row_start[i]=excl;
      cursor[i]=excl;
      inv_sq[i]=1.f/sqrtf((float)(v+1));
    }
    __syncthreads();
    if(tid==1023) base_sh=base+incl;
    __syncthreads();
  }
  if(tid==0) row_start[NN]=base_sh;
}

// ---------------- CSR scatter ----------------
__global__ void k_csr(const int* __restrict__ src, const int* __restrict__ dst,
    int* __restrict__ cursor, int* __restrict__ csr_src){
  int e=blockIdx.x*256+threadIdx.x;
  if(e<NE){
    int d=dst[e];
    int p=atomicAdd(&cursor[d],1);
    csr_src[p]=src[e];
  }
}

// ---------------- 128x128 transpose (Wbil^T) ----------------
__global__ void k_transpose(const float* __restrict__ W, float* __restrict__ Wt){
  int idx=blockIdx.x*256+threadIdx.x;
  if(idx<DD*DD){
    int k=idx>>7, c=idx&127;
    Wt[idx]=W[c*DD+k];
  }
}

// ---------------- fp32 GEMM, 64 rows/block, 8x4 acc/thread --------------
template<int IN_SIG,int ACT,int OUT_BF16,int FUSE_SCORE>
__global__ __launch_bounds__(256) void k_gemm64(const float* __restrict__ A,
    const float* __restrict__ W, const float* __restrict__ bias,
    float* __restrict__ outf, ushort16* __restrict__ outb,
    const float* __restrict__ aparam, const float* __restrict__ hp,
    const float* __restrict__ bbil, float* __restrict__ score){
  __shared__ float Al[64][DD];            // 32 KB
  int tid=threadIdx.x;
  int row0=blockIdx.x*64;
  const float4* A4=(const float4*)(A+(size_t)row0*DD);
  float4* Al4=(float4*)&Al[0][0];
  #pragma unroll
  for(int i=0;i<8;i++){
    int idx=i*256+tid;
    int r=idx>>5;
    float4 v=make_float4(0.f,0.f,0.f,0.f);
    if(row0+r<NN) v=A4[idx];
    if(IN_SIG){ v.x=sigmoidf(v.x); v.y=sigmoidf(v.y); v.z=sigmoidf(v.z); v.w=sigmoidf(v.w); }
    Al4[idx]=v;
  }
  __syncthreads();
  int tx=tid&31, ty=tid>>5;
  float acc[8][4];
  #pragma unroll
  for(int i=0;i<8;i++){
    #pragma unroll
    for(int j=0;j<4;j++) acc[i][j]=0.f;
  }
  const float4* Wp=(const float4*)W;
  #pragma unroll 2
  for(int k=0;k<DD;k+=4){
    float4 w0=Wp[(k+0)*32+tx];
    float4 w1=Wp[(k+1)*32+tx];
    float4 w2=Wp[(k+2)*32+tx];
    float4 w3=Wp[(k+3)*32+tx];
    #pragma unroll
    for(int i=0;i<8;i++){
      float4 a=*(const float4*)&Al[ty*8+i][k];
      acc[i][0]+=a.x*w0.x+a.y*w1.x+a.z*w2.x+a.w*w3.x;
      acc[i][1]+=a.x*w0.y+a.y*w1.y+a.z*w2.y+a.w*w3.y;
      acc[i][2]+=a.x*w0.z+a.y*w1.z+a.z*w2.z+a.w*w3.z;
      acc[i][3]+=a.x*w0.w+a.y*w1.w+a.z*w2.w+a.w*w3.w;
    }
  }
  if(FUSE_SCORE){
    float bb=bbil[0];
    #pragma unroll
    for(int i=0;i<8;i++){
      int r=row0+ty*8+i;
      float p=0.f;
      if(r<NN){
        float4 h=*(const float4*)&hp[(size_t)r*DD+tx*4];
        p=acc[i][0]*h.x+acc[i][1]*h.y+acc[i][2]*h.z+acc[i][3]*h.w;
      }
      #pragma unroll
      for(int off=16;off;off>>=1) p+=__shfl_xor(p,off,64);
      if(tx==0 && r<NN) score[r]=sigmoidf(p+bb);
    }
    return;
  }
  float4 bv=make_float4(0.f,0.f,0.f,0.f);
  if(bias) bv=*(const float4*)&bias[tx*4];
  float ap=ACT?aparam[0]:0.f;
  #pragma unroll
  for(int i=0;i<8;i++){
    int r=row0+ty*8+i;
    if(r<NN){
      float4 o;
      o.x=acc[i][0]+bv.x; o.y=acc[i][1]+bv.y; o.z=acc[i][2]+bv.z; o.w=acc[i][3]+bv.w;
      if(ACT){
        o.x=o.x>=0.f?o.x:ap*o.x; o.y=o.y>=0.f?o.y:ap*o.y;
        o.z=o.z>=0.f?o.z:ap*o.z; o.w=o.w>=0.f?o.w:ap*o.w;
      }
      if(OUT_BF16){
        uint32 p0=((uint32)f2b(o.y)<<16)|f2b(o.x);
        uint32 p1=((uint32)f2b(o.w)<<16)|f2b(o.z);
        uint2 pk; pk.x=p0; pk.y=p1;
        *(uint2*)&outb[(size_t)r*DD+tx*4]=pk;
      } else {
        *(float4*)&outf[(size_t)r*DD+tx*4]=o;
      }
    }
  }
}

// ---------------- fp32 GCN aggregation: 2 edges per dwordx4 --------------
__global__ __launch_bounds__(256) void k_agg_f32(const float* __restrict__ xw,
    const int* __restrict__ row_start, const int* __restrict__ csr,
    const float* __restrict__ inv, const float* __restrict__ bias,
    float* __restrict__ outp){
  int node=blockIdx.x*4+(threadIdx.x>>6);
  if(node>=NN) return;
  int lane=threadIdx.x&63;
  int g=lane>>5, li=lane&31;           // 2 groups of 32 lanes; cols li*4..+3
  int rs=row_start[node], re=row_start[node+1];
  float a0=0.f,a1=0.f,a2=0.f,a3=0.f;
  int j=rs;
  for(; j+3<re; j+=4){
    int sA=csr[j+g], sB=csr[j+2+g];
    float wA=inv[sA], wB=inv[sB];
    float4 vA=*(const float4*)&xw[(size_t)sA*DD+li*4];
    float4 vB=*(const float4*)&xw[(size_t)sB*DD+li*4];
    a0+=vA.x*wA+vB.x*wB; a1+=vA.y*wA+vB.y*wB;
    a2+=vA.z*wA+vB.z*wB; a3+=vA.w*wA+vB.w*wB;
  }
  for(; j+1<re; j+=2){
    int s=csr[j+g];
    float w=inv[s];
    float4 v=*(const float4*)&xw[(size_t)s*DD+li*4];
    a0+=v.x*w; a1+=v.y*w; a2+=v.z*w; a3+=v.w*w;
  }
  if(j<re && g==0){
    int s=csr[j]; float w=inv[s];
    float4 v=*(const float4*)&xw[(size_t)s*DD+li*4];
    a0+=v.x*w; a1+=v.y*w; a2+=v.z*w; a3+=v.w*w;
  }
  if(g==0){
    float wd=inv[node];
    float4 v=*(const float4*)&xw[(size_t)node*DD+li*4];
    a0+=v.x*wd; a1+=v.y*wd; a2+=v.z*wd; a3+=v.w*wd;
  }
  a0+=__shfl_xor(a0,32,64); a1+=__shfl_xor(a1,32,64);
  a2+=__shfl_xor(a2,32,64); a3+=__shfl_xor(a3,32,64);
  if(g==0){
    float wn=inv[node];
    float4 bv=*(const float4*)&bias[li*4];
    float4 o;
    o.x=a0*wn+bv.x; o.y=a1*wn+bv.y; o.z=a2*wn+bv.z; o.w=a3*wn+bv.w;
    *(float4*)&outp[(size_t)node*DD+li*4]=o;
  }
}

// ---------------- bf16 GCN aggregation: 4 edges per dwordx4 --------------
// MODE 1: out = sel[node] ? (agg+bias)*score : 0
// MODE 2: out = agg(skip !sel[s]) + bias + addbuf
template<int MODE>
__global__ __launch_bounds__(256) void k_agg_b16(const uint32* __restrict__ xwb,
    const int* __restrict__ row_start, const int* __restrict__ csr,
    const float* __restrict__ inv, const float* __restrict__ bias,
    float* __restrict__ outp, const float* __restrict__ score,
    const unsigned char* __restrict__ sel, const float* __restrict__ addbuf){
  int node=blockIdx.x*4+(threadIdx.x>>6);
  if(node>=NN) return;
  int lane=threadIdx.x&63;
  if(MODE==1 && !sel[node]){
    float2 z; z.x=0.f; z.y=0.f;
    *(float2*)&outp[(size_t)node*DD+lane*2]=z;
    return;
  }
  int g=lane>>4, li=lane&15;           // 4 groups of 16 lanes; cols li*8..+7
  int rs=row_start[node], re=row_start[node+1];
  float a[8];
  #pragma unroll
  for(int c=0;c<8;c++) a[c]=0.f;
  int j=rs;
  for(; j+7<re; j+=8){
    int sA=csr[j+g], sB=csr[j+4+g];
    if(MODE!=2 || sel[sA]){
      float w=inv[sA];
      uint4 u=*(const uint4*)(xwb+(size_t)sA*64+li*4);
      addbf2(a[0],a[1],u.x,w); addbf2(a[2],a[3],u.y,w);
      addbf2(a[4],a[5],u.z,w); addbf2(a[6],a[7],u.w,w);
    }
    if(MODE!=2 || sel[sB]){
      float w=inv[sB];
      uint4 u=*(const uint4*)(xwb+(size_t)sB*64+li*4);
      addbf2(a[0],a[1],u.x,w); addbf2(a[2],a[3],u.y,w);
      addbf2(a[4],a[5],u.z,w); addbf2(a[6],a[7],u.w,w);
    }
  }
  for(; j+3<re; j+=4){
    int s=csr[j+g];
    if(MODE!=2 || sel[s]){
      float w=inv[s];
      uint4 u=*(const uint4*)(xwb+(size_t)s*64+li*4);
      addbf2(a[0],a[1],u.x,w); addbf2(a[2],a[3],u.y,w);
      addbf2(a[4],a[5],u.z,w); addbf2(a[6],a[7],u.w,w);
    }
  }
  int rem=re-j;
  if(g<rem){
    int s=csr[j+g];
    if(MODE!=2 || sel[s]){
      float w=inv[s];
      uint4 u=*(const uint4*)(xwb+(size_t)s*64+li*4);
      addbf2(a[0],a[1],u.x,w); addbf2(a[2],a[3],u.y,w);
      addbf2(a[4],a[5],u.z,w); addbf2(a[6],a[7],u.w,w);
    }
  }
  if(g==0 && (MODE!=2 || sel[node])){
    float wd=inv[node];
    uint4 u=*(const uint4*)(xwb+(size_t)node*64+li*4);
    addbf2(a[0],a[1],u.x,wd); addbf2(a[2],a[3],u.y,wd);
    addbf2(a[4],a[5],u.z,wd); addbf2(a[6],a[7],u.w,wd);
  }
  #pragma unroll
  for(int c=0;c<8;c++){
    a[c]+=__shfl_xor(a[c],16,64);
    a[c]+=__shfl_xor(a[c],32,64);
  }
  if(g<2){
    float wn=inv[node];
    int cb=li*8+g*4;
    float4 bv=*(const float4*)&bias[cb];
    float r0=a[g*4+0]*wn+bv.x, r1=a[g*4+1]*wn+bv.y;
    float r2=a[g*4+2]*wn+bv.z, r3=a[g*4+3]*wn+bv.w;
    if(MODE==1){
      float sc=score[node];
      r0*=sc; r1*=sc; r2*=sc; r3*=sc;
    } else {
      float4 ad=*(const float4*)&addbuf[(size_t)node*DD+cb];
      r0+=ad.x; r1+=ad.y; r2+=ad.z; r3+=ad.w;
    }
    float4 o; o.x=r0; o.y=r1; o.z=r2; o.w=r3;
    *(float4*)&outp[(size_t)node*DD+cb]=o;
  }
}

// ---------------- 3-pass radix select, LDS-privatized histograms ----------
// pass0: bits[31:20] (4096) ; pass1: bits[19:8] (4096) ; pass2: bits[7:0] (256)
template<int NB,int PASS>
__global__ __launch_bounds__(256) void k_hist(const float* __restrict__ score,
    int* __restrict__ ghist, const int* __restrict__ ctrl){
  __shared__ int lh[NB];
  int tid=threadIdx.x;
  for(int i=tid;i<NB;i+=256) lh[i]=0;
  __syncthreads();
  int p0=0,p01=0;
  if(PASS==1) p0=ctrl[0];
  if(PASS==2) p01=ctrl[2];
  for(int i=blockIdx.x*256+tid; i<NN; i+=gridDim.x*256){
    unsigned b=__float_as_uint(score[i]);   // scores>0: uint order == value order
    if(PASS==0) atomicAdd(&lh[b>>20],1);
    else if(PASS==1){ if((int)(b>>20)==p0) atomicAdd(&lh[(b>>8)&0xFFF],1); }
    else { if((int)(b>>8)==p01) atomicAdd(&lh[b&0xFF],1); }
  }
  __syncthreads();
  for(int i=tid;i<NB;i+=256){ int v=lh[i]; if(v) atomicAdd(&ghist[i],v); }
}

template<int NB,int PASS>
__global__ void k_findb(const int* __restrict__ hist, int* __restrict__ ctrl){
  const int NT=NB/4;
  __shared__ int gsum[NT];
  int t=threadIdx.x;
  int s=hist[t*4]+hist[t*4+1]+hist[t*4+2]+hist[t*4+3];
  int x=s; gsum[t]=x; __syncthreads();
  for(int off=1;off<NT;off<<=1){
    int y=(t+off<NT)?gsum[t+off]:0;
    __syncthreads();
    x+=y; gsum[t]=x; __syncthreads();
  }
  int base;
  if(PASS==0) base=0; else if(PASS==1) base=ctrl[1]; else base=ctrl[3];
  int above=base+((t<NT-1)?gsum[t+1]:0);
  int incl=base+gsum[t];
  if(above<KSEL && incl>=KSEL){
    int c=above, B=0;
    for(int b=3;b>=0;b--){
      int hb=hist[t*4+b];
      if(c+hb>=KSEL){ B=t*4+b; break; }
      c+=hb;
    }
    if(PASS==0){ ctrl[0]=B; ctrl[1]=c; }
    else if(PASS==1){ ctrl[2]=(ctrl[0]<<12)|B; ctrl[3]=c; }
    else { ctrl[4]=(int)((((unsigned)ctrl[2])<<8)|(unsigned)B); ctrl[5]=KSEL-c; }
  }
}

__global__ void k_sel(const float* __restrict__ score, int* __restrict__ ctrl,
                      int* __restrict__ tie_list, unsigned char* __restrict__ sel){
  int i=blockIdx.x*256+threadIdx.x;
  if(i>=NN) return;
  unsigned b=__float_as_uint(score[i]);
  unsigned thr=(unsigned)ctrl[4];
  if(b>thr){ sel[i]=1; }
  else if(b==thr){
    sel[i]=0;
    int p=atomicAdd(&ctrl[6],1);
    if(p<4096) tie_list[p]=i;
  } else sel[i]=0;
}

__global__ __launch_bounds__(256) void k_tie(const int* __restrict__ ctrl,
    const int* __restrict__ tie_list, unsigned char* __restrict__ sel){
  int m=ctrl[6]; if(m>4096) m=4096;
  int needed=ctrl[5];
  for(int t=threadIdx.x; t<m; t+=blockDim.x){
    int idx=tie_list[t];
    int rank=0;
    for(int j=0;j<m;j++) rank+=(tie_list[j]<idx)?1:0;
    if(rank<needed) sel[idx]=1;
  }
}

// ============================================================================
extern "C" void kernel_launch(void* const* d_in, const int* in_sizes, int n_in,
                              void* d_out, int out_size, void* d_ws, size_t ws_size,
                              hipStream_t stream){
  const float* feat   =(const float*)d_in[0];
  const int*   ei     =(const int*)  d_in[2];
  const int*   src    = ei;
  const int*   dst    = ei + NE;
  const float* Wd     =(const float*)d_in[3];
  const float* bd     =(const float*)d_in[4];
  const float* prelu_a=(const float*)d_in[5];
  const float* Wbil   =(const float*)d_in[6];
  const float* bbil   =(const float*)d_in[7];
  const float* Wg1    =(const float*)d_in[8];
  const float* bg1    =(const float*)d_in[9];
  const float* Wg2    =(const float*)d_in[10];
  const float* bg2    =(const float*)d_in[11];
  const float* Wg3    =(const float*)d_in[12];
  const float* bg3    =(const float*)d_in[13];
  float* out=(float*)d_out;

  char* p=(char*)d_ws;
  auto alloc=[&](size_t bytes)->void*{ void* r=(void*)p; p+=((bytes+255)/256)*256; return r; };
  float* h_pos   =(float*)alloc((size_t)NN*DD*4);
  float* embed   =(float*)alloc((size_t)NN*DD*4);
  float* xw      =(float*)alloc((size_t)NN*DD*4);
  float* score   =(float*)alloc((size_t)NN*4);
  float* inv_sq  =(float*)alloc((size_t)NN*4);
  float* WbT     =(float*)alloc((size_t)DD*DD*4);
  int*   deg     =(int*)  alloc((size_t)NN*4);
  int*   row_st  =(int*)  alloc((size_t)(NN+1)*4);
  int*   cursor  =(int*)  alloc((size_t)NN*4);
  int*   csr_src =(int*)  alloc((size_t)NE*4);
  int*   ctrl    =(int*)  alloc(64);
  int*   hist0   =(int*)  alloc(4096*4);
  int*   hist1   =(int*)  alloc(4096*4);
  int*   hist2   =(int*)  alloc(256*4);
  int*   tie_list=(int*)  alloc(4096*4);
  unsigned char* sel=(unsigned char*)alloc(NN);
  ushort16* xwb  =(ushort16*)xw;
  float* fine = out;

  const int EB=(NE+255)/256;
  const int NB=(NN+255)/256;
  const int GB=(NN+63)/64;
  const int AB=(NN+3)/4;

  hipMemsetAsync(deg, 0, (size_t)NN*4, stream);
  // ctrl + hist0 + hist1 + hist2 are contiguous (256B-aligned chunks): one memset
  hipMemsetAsync(ctrl, 0, (size_t)((char*)tie_list-(char*)ctrl), stream);

  k_deg<<<EB,256,0,stream>>>(dst, deg);
  k_scan<<<1,1024,0,stream>>>(deg, row_st, cursor, inv_sq);
  k_csr<<<EB,256,0,stream>>>(src, dst, cursor, csr_src);
  k_transpose<<<64,256,0,stream>>>(Wbil, WbT);

  // h_pos = prelu(feat @ Wd + bd)
  k_gemm64<0,1,0,0><<<GB,256,0,stream>>>(feat, Wd, bd, h_pos, nullptr, prelu_a, nullptr, nullptr, nullptr);
  // embed = gcn1(h_pos)
  k_gemm64<0,0,0,0><<<GB,256,0,stream>>>(h_pos, Wg1, nullptr, xw, nullptr, nullptr, nullptr, nullptr, nullptr);
  k_agg_f32<<<AB,256,0,stream>>>(xw, row_st, csr_src, inv_sq, bg1, embed);
  // score = sigmoid(rowdot(h_pos, sigmoid(embed)@Wbil^T) + bbil)   [fused]
  k_gemm64<1,0,0,1><<<GB,256,0,stream>>>(embed, WbT, nullptr, nullptr, nullptr, nullptr, h_pos, bbil, score);
  // top-k: 3-pass LDS-privatized radix select
  k_hist<4096,0><<<64,256,0,stream>>>(score, hist0, ctrl);
  k_findb<4096,0><<<1,1024,0,stream>>>(hist0, ctrl);
  k_hist<4096,1><<<64,256,0,stream>>>(score, hist1, ctrl);
  k_findb<4096,1><<<1,1024,0,stream>>>(hist1, ctrl);
  k_hist<256,2><<<64,256,0,stream>>>(score, hist2, ctrl);
  k_findb<256,2><<<1,64,0,stream>>>(hist2, ctrl);
  k_sel<<<NB,256,0,stream>>>(score, ctrl, tie_list, sel);
  k_tie<<<1,256,0,stream>>>(ctrl, tie_list, sel);
  // fine = sel ? gcn2(embed)*score : 0   (bf16 xw2)
  k_gemm64<0,0,1,0><<<GB,256,0,stream>>>(embed, Wg2, nullptr, nullptr, xwb, nullptr, nullptr, nullptr, nullptr);
  k_agg_b16<1><<<AB,256,0,stream>>>((const uint32*)xwb, row_st, csr_src, inv_sq, bg2, fine, score, sel, nullptr);
  // out = gcn3(fine) + embed             (bf16 xw3, skip exact-zero rows)
  k_gemm64<0,0,1,0><<<GB,256,0,stream>>>(fine, Wg3, nullptr, nullptr, xwb, nullptr, nullptr, nullptr, nullptr);
  k_agg_b16<2><<<AB,256,0,stream>>>((const uint32*)xwb, row_st, csr_src, inv_sq, bg3, out, nullptr, sel, embed);
}

// Round 4
// 373.241 us; speedup vs baseline: 1.8453x; 1.2914x over previous
//
#include <hip/hip_runtime.h>
#include <hip/hip_bf16.h>

#define NN 50000
#define NE 800000
#define DD 128
#define KSEL 25000
#define NBK 391                 // buckets of 128 nodes
#define NBLKA 98                // (NE+8191)/8192

typedef unsigned int uint32;
typedef unsigned short ushort16;

__device__ __forceinline__ float sigmoidf(float x){ return 1.f/(1.f+__expf(-x)); }

__device__ __forceinline__ unsigned short f2b(float f){
  union{float f; unsigned u;} v; v.f=f;
  unsigned r=(v.u + 0x7fffu + ((v.u>>16)&1u))>>16;
  return (unsigned short)r;
}

__device__ __forceinline__ void addbf2(float&lo,float&hi,uint32 u,float w){
  lo+=__uint_as_float(u<<16)*w;
  hi+=__uint_as_float(u&0xffff0000u)*w;
}

// ================= graph build: bucketed counting sort =================
// bucket b = nodes [b*128, b*128+128)
__global__ __launch_bounds__(1024) void k_bcount(const int* __restrict__ dst,
    int* __restrict__ btot, int* __restrict__ blkcnt){
  __shared__ int h[NBK];
  int tid=threadIdx.x;
  for(int i=tid;i<NBK;i+=1024) h[i]=0;
  __syncthreads();
  int e0=blockIdx.x*8192;
  #pragma unroll
  for(int t=0;t<8;t++){
    int e=e0+t*1024+tid;
    if(e<NE) atomicAdd(&h[dst[e]>>7],1);
  }
  __syncthreads();
  for(int i=tid;i<NBK;i+=1024){
    int c=h[i];
    blkcnt[blockIdx.x*NBK+i]=c;
    if(c) atomicAdd(&btot[i],c);
  }
}

__global__ __launch_bounds__(512) void k_bscan(const int* __restrict__ btot,
    int* __restrict__ boff, const int* __restrict__ blkcnt, int* __restrict__ blkbase,
    int* __restrict__ row_start){
  __shared__ int sdata[512];
  int tid=threadIdx.x;
  int v=(tid<NBK)?btot[tid]:0;
  sdata[tid]=v; __syncthreads();
  for(int off=1;off<512;off<<=1){
    int y=(tid>=off)?sdata[tid-off]:0;
    __syncthreads();
    sdata[tid]+=y;
    __syncthreads();
  }
  int excl=sdata[tid]-v;
  if(tid<NBK) boff[tid]=excl;
  if(tid==NBK-1){ boff[NBK]=excl+v; row_start[NN]=NE; }
  if(tid<NBK){
    int run=excl;
    for(int b=0;b<NBLKA;b++){
      int c=blkcnt[b*NBK+tid];
      blkbase[b*NBK+tid]=run;
      run+=c;
    }
  }
}

__global__ __launch_bounds__(1024) void k_bscatter(const int* __restrict__ src,
    const int* __restrict__ dst, const int* __restrict__ blkbase, uint2* __restrict__ pairs){
  __shared__ int cur[NBK];
  int tid=threadIdx.x;
  for(int i=tid;i<NBK;i+=1024) cur[i]=blkbase[blockIdx.x*NBK+i];
  __syncthreads();
  int e0=blockIdx.x*8192;
  #pragma unroll
  for(int t=0;t<8;t++){
    int e=e0+t*1024+tid;
    if(e<NE){
      int d=dst[e];
      int p=atomicAdd(&cur[d>>7],1);
      uint2 pr; pr.x=(unsigned)src[e]; pr.y=(unsigned)d;
      pairs[p]=pr;
    }
  }
}

__global__ __launch_bounds__(256) void k_bfinal(const uint2* __restrict__ pairs,
    const int* __restrict__ boff, int* __restrict__ row_start,
    float* __restrict__ inv_sq, int* __restrict__ csr_src){
  __shared__ int degl[128];
  __shared__ int cur[128];
  __shared__ int ssum[2];
  int b=blockIdx.x, tid=threadIdx.x;
  int lo=boff[b], hi=boff[b+1];
  if(tid<128) degl[tid]=0;
  __syncthreads();
  for(int e=lo+tid;e<hi;e+=256) atomicAdd(&degl[pairs[e].y&127],1);
  __syncthreads();
  int v=0,x=0;
  if(tid<128){
    v=degl[tid]; x=v;
    #pragma unroll
    for(int off=1;off<64;off<<=1){
      int y=__shfl_up(x,off,64);
      if((tid&63)>=off) x+=y;
    }
    if((tid&63)==63) ssum[tid>>6]=x;
  }
  __syncthreads();
  if(tid<128){
    int incl=x+((tid>=64)?ssum[0]:0);
    int node=b*128+tid;
    int excl=lo+incl-v;
    if(node<NN){
      row_start[node]=excl;
      cur[tid]=excl;
      inv_sq[node]=1.f/sqrtf((float)(v+1));
    }
  }
  __syncthreads();
  for(int e=lo+tid;e<hi;e+=256){
    uint2 pr=pairs[e];
    int p=atomicAdd(&cur[pr.y&127],1);
    csr_src[p]=(int)pr.x;
  }
}

// ---------------- 128x128 transpose (Wbil^T) ----------------
__global__ void k_transpose(const float* __restrict__ W, float* __restrict__ Wt){
  int idx=blockIdx.x*256+threadIdx.x;
  if(idx<DD*DD){
    int k=idx>>7, c=idx&127;
    Wt[idx]=W[c*DD+k];
  }
}

// ============ fp32 GEMM v2: 128x128 tile, 8x8 per thread ============
// A in LDS [128][132] (conflict-free: concurrent rows differ by 1 -> bank+4)
// W streamed from global (L1-resident strip), VMEM pipe parallel to LDS pipe.
template<int IN_SIG,int ACT,int OUT_BF16,int FUSE_SCORE>
__global__ __launch_bounds__(256) void k_gemm128(const float* __restrict__ A,
    const float* __restrict__ W, const float* __restrict__ bias,
    float* __restrict__ outf, ushort16* __restrict__ outb,
    const float* __restrict__ aparam, const float* __restrict__ hp,
    const float* __restrict__ bbil, float* __restrict__ score){
  __shared__ float Al[128][132];          // 67.6 KB -> 2 blocks/CU
  int tid=threadIdx.x;
  int row0=blockIdx.x*128;
  {
    const float4* A4=(const float4*)(A+(size_t)row0*DD);
    #pragma unroll
    for(int i=0;i<16;i++){
      int idx=i*256+tid;                  // 0..4095
      int r=idx>>5, c=(idx&31)*4;
      float4 v=make_float4(0.f,0.f,0.f,0.f);
      if(row0+r<NN) v=A4[idx];
      if(IN_SIG){ v.x=sigmoidf(v.x); v.y=sigmoidf(v.y); v.z=sigmoidf(v.z); v.w=sigmoidf(v.w); }
      *(float4*)&Al[r][c]=v;
    }
  }
  __syncthreads();
  int tx=tid&15, ty=tid>>4;               // cols tx*8..+7 ; rows ty+16*i
  float acc[8][8];
  #pragma unroll
  for(int i=0;i<8;i++)
    #pragma unroll
    for(int c=0;c<8;c++) acc[i][c]=0.f;

  for(int k=0;k<DD;k+=4){
    float wv[4][8];
    #pragma unroll
    for(int r=0;r<4;r++){
      float4 lo=*(const float4*)&W[(size_t)(k+r)*DD+tx*8];
      float4 hi=*(const float4*)&W[(size_t)(k+r)*DD+tx*8+4];
      wv[r][0]=lo.x; wv[r][1]=lo.y; wv[r][2]=lo.z; wv[r][3]=lo.w;
      wv[r][4]=hi.x; wv[r][5]=hi.y; wv[r][6]=hi.z; wv[r][7]=hi.w;
    }
    #pragma unroll
    for(int i=0;i<8;i++){
      float4 a=*(const float4*)&Al[ty+16*i][k];
      #pragma unroll
      for(int c=0;c<8;c++)
        acc[i][c]+=a.x*wv[0][c]+a.y*wv[1][c]+a.z*wv[2][c]+a.w*wv[3][c];
    }
  }

  if(FUSE_SCORE){
    float bb=bbil[0];
    #pragma unroll
    for(int i=0;i<8;i++){
      int r=row0+ty+16*i;
      float p=0.f;
      if(r<NN){
        float4 h0=*(const float4*)&hp[(size_t)r*DD+tx*8];
        float4 h1=*(const float4*)&hp[(size_t)r*DD+tx*8+4];
        p=acc[i][0]*h0.x+acc[i][1]*h0.y+acc[i][2]*h0.z+acc[i][3]*h0.w
         +acc[i][4]*h1.x+acc[i][5]*h1.y+acc[i][6]*h1.z+acc[i][7]*h1.w;
      }
      p+=__shfl_xor(p,1,64); p+=__shfl_xor(p,2,64);
      p+=__shfl_xor(p,4,64); p+=__shfl_xor(p,8,64);
      if(tx==0 && r<NN) score[r]=sigmoidf(p+bb);
    }
    return;
  }
  float bl[8]={0,0,0,0,0,0,0,0};
  if(bias){
    float4 b0=*(const float4*)&bias[tx*8];
    float4 b1=*(const float4*)&bias[tx*8+4];
    bl[0]=b0.x; bl[1]=b0.y; bl[2]=b0.z; bl[3]=b0.w;
    bl[4]=b1.x; bl[5]=b1.y; bl[6]=b1.z; bl[7]=b1.w;
  }
  float ap=ACT?aparam[0]:0.f;
  #pragma unroll
  for(int i=0;i<8;i++){
    int r=row0+ty+16*i;
    if(r<NN){
      float o[8];
      #pragma unroll
      for(int c=0;c<8;c++){
        float t=acc[i][c]+bl[c];
        if(ACT) t=t>=0.f?t:ap*t;
        o[c]=t;
      }
      if(OUT_BF16){
        uint4 pk;
        pk.x=((uint32)f2b(o[1])<<16)|f2b(o[0]);
        pk.y=((uint32)f2b(o[3])<<16)|f2b(o[2]);
        pk.z=((uint32)f2b(o[5])<<16)|f2b(o[4]);
        pk.w=((uint32)f2b(o[7])<<16)|f2b(o[6]);
        *(uint4*)&outb[(size_t)r*DD+tx*8]=pk;
      } else {
        float4 q0; q0.x=o[0]; q0.y=o[1]; q0.z=o[2]; q0.w=o[3];
        float4 q1; q1.x=o[4]; q1.y=o[5]; q1.z=o[6]; q1.w=o[7];
        *(float4*)&outf[(size_t)r*DD+tx*8]=q0;
        *(float4*)&outf[(size_t)r*DD+tx*8+4]=q1;
      }
    }
  }
}

// ---------------- fp32 GCN aggregation: 2 edges per dwordx4 --------------
__global__ __launch_bounds__(256) void k_agg_f32(const float* __restrict__ xw,
    const int* __restrict__ row_start, const int* __restrict__ csr,
    const float* __restrict__ inv, const float* __restrict__ bias,
    float* __restrict__ outp){
  int node=blockIdx.x*4+(threadIdx.x>>6);
  if(node>=NN) return;
  int lane=threadIdx.x&63;
  int g=lane>>5, li=lane&31;
  int rs=row_start[node], re=row_start[node+1];
  float a0=0.f,a1=0.f,a2=0.f,a3=0.f;
  int j=rs;
  for(; j+3<re; j+=4){
    int sA=csr[j+g], sB=csr[j+2+g];
    float wA=inv[sA], wB=inv[sB];
    float4 vA=*(const float4*)&xw[(size_t)sA*DD+li*4];
    float4 vB=*(const float4*)&xw[(size_t)sB*DD+li*4];
    a0+=vA.x*wA+vB.x*wB; a1+=vA.y*wA+vB.y*wB;
    a2+=vA.z*wA+vB.z*wB; a3+=vA.w*wA+vB.w*wB;
  }
  for(; j+1<re; j+=2){
    int s=csr[j+g];
    float w=inv[s];
    float4 v=*(const float4*)&xw[(size_t)s*DD+li*4];
    a0+=v.x*w; a1+=v.y*w; a2+=v.z*w; a3+=v.w*w;
  }
  if(j<re && g==0){
    int s=csr[j]; float w=inv[s];
    float4 v=*(const float4*)&xw[(size_t)s*DD+li*4];
    a0+=v.x*w; a1+=v.y*w; a2+=v.z*w; a3+=v.w*w;
  }
  if(g==0){
    float wd=inv[node];
    float4 v=*(const float4*)&xw[(size_t)node*DD+li*4];
    a0+=v.x*wd; a1+=v.y*wd; a2+=v.z*wd; a3+=v.w*wd;
  }
  a0+=__shfl_xor(a0,32,64); a1+=__shfl_xor(a1,32,64);
  a2+=__shfl_xor(a2,32,64); a3+=__shfl_xor(a3,32,64);
  if(g==0){
    float wn=inv[node];
    float4 bv=*(const float4*)&bias[li*4];
    float4 o;
    o.x=a0*wn+bv.x; o.y=a1*wn+bv.y; o.z=a2*wn+bv.z; o.w=a3*wn+bv.w;
    *(float4*)&outp[(size_t)node*DD+li*4]=o;
  }
}

// ---------------- bf16 GCN aggregation: 4 edges per dwordx4 --------------
template<int MODE>
__global__ __launch_bounds__(256) void k_agg_b16(const uint32* __restrict__ xwb,
    const int* __restrict__ row_start, const int* __restrict__ csr,
    const float* __restrict__ inv, const float* __restrict__ bias,
    float* __restrict__ outp, const float* __restrict__ score,
    const unsigned char* __restrict__ sel, const float* __restrict__ addbuf){
  int node=blockIdx.x*4+(threadIdx.x>>6);
  if(node>=NN) return;
  int lane=threadIdx.x&63;
  if(MODE==1 && !sel[node]){
    float2 z; z.x=0.f; z.y=0.f;
    *(float2*)&outp[(size_t)node*DD+lane*2]=z;
    return;
  }
  int g=lane>>4, li=lane&15;
  int rs=row_start[node], re=row_start[node+1];
  float a[8];
  #pragma unroll
  for(int c=0;c<8;c++) a[c]=0.f;
  int j=rs;
  for(; j+7<re; j+=8){
    int sA=csr[j+g], sB=csr[j+4+g];
    if(MODE!=2 || sel[sA]){
      float w=inv[sA];
      uint4 u=*(const uint4*)(xwb+(size_t)sA*64+li*4);
      addbf2(a[0],a[1],u.x,w); addbf2(a[2],a[3],u.y,w);
      addbf2(a[4],a[5],u.z,w); addbf2(a[6],a[7],u.w,w);
    }
    if(MODE!=2 || sel[sB]){
      float w=inv[sB];
      uint4 u=*(const uint4*)(xwb+(size_t)sB*64+li*4);
      addbf2(a[0],a[1],u.x,w); addbf2(a[2],a[3],u.y,w);
      addbf2(a[4],a[5],u.z,w); addbf2(a[6],a[7],u.w,w);
    }
  }
  for(; j+3<re; j+=4){
    int s=csr[j+g];
    if(MODE!=2 || sel[s]){
      float w=inv[s];
      uint4 u=*(const uint4*)(xwb+(size_t)s*64+li*4);
      addbf2(a[0],a[1],u.x,w); addbf2(a[2],a[3],u.y,w);
      addbf2(a[4],a[5],u.z,w); addbf2(a[6],a[7],u.w,w);
    }
  }
  int rem=re-j;
  if(g<rem){
    int s=csr[j+g];
    if(MODE!=2 || sel[s]){
      float w=inv[s];
      uint4 u=*(const uint4*)(xwb+(size_t)s*64+li*4);
      addbf2(a[0],a[1],u.x,w); addbf2(a[2],a[3],u.y,w);
      addbf2(a[4],a[5],u.z,w); addbf2(a[6],a[7],u.w,w);
    }
  }
  if(g==0 && (MODE!=2 || sel[node])){
    float wd=inv[node];
    uint4 u=*(const uint4*)(xwb+(size_t)node*64+li*4);
    addbf2(a[0],a[1],u.x,wd); addbf2(a[2],a[3],u.y,wd);
    addbf2(a[4],a[5],u.z,wd); addbf2(a[6],a[7],u.w,wd);
  }
  #pragma unroll
  for(int c=0;c<8;c++){
    a[c]+=__shfl_xor(a[c],16,64);
    a[c]+=__shfl_xor(a[c],32,64);
  }
  if(g<2){
    float wn=inv[node];
    int cb=li*8+g*4;
    float4 bv=*(const float4*)&bias[cb];
    float r0=a[g*4+0]*wn+bv.x, r1=a[g*4+1]*wn+bv.y;
    float r2=a[g*4+2]*wn+bv.z, r3=a[g*4+3]*wn+bv.w;
    if(MODE==1){
      float sc=score[node];
      r0*=sc; r1*=sc; r2*=sc; r3*=sc;
    } else {
      float4 ad=*(const float4*)&addbuf[(size_t)node*DD+cb];
      r0+=ad.x; r1+=ad.y; r2+=ad.z; r3+=ad.w;
    }
    float4 o; o.x=r0; o.y=r1; o.z=r2; o.w=r3;
    *(float4*)&outp[(size_t)node*DD+cb]=o;
  }
}

// ---------------- 3-pass radix select, LDS-privatized ----------
template<int NB,int PASS>
__global__ __launch_bounds__(256) void k_hist(const float* __restrict__ score,
    int* __restrict__ ghist, const int* __restrict__ ctrl){
  __shared__ int lh[NB];
  int tid=threadIdx.x;
  for(int i=tid;i<NB;i+=256) lh[i]=0;
  __syncthreads();
  int p0=0,p01=0;
  if(PASS==1) p0=ctrl[0];
  if(PASS==2) p01=ctrl[2];
  for(int i=blockIdx.x*256+tid; i<NN; i+=gridDim.x*256){
    unsigned b=__float_as_uint(score[i]);
    if(PASS==0) atomicAdd(&lh[b>>20],1);
    else if(PASS==1){ if((int)(b>>20)==p0) atomicAdd(&lh[(b>>8)&0xFFF],1); }
    else { if((int)(b>>8)==p01) atomicAdd(&lh[b&0xFF],1); }
  }
  __syncthreads();
  for(int i=tid;i<NB;i+=256){ int v=lh[i]; if(v) atomicAdd(&ghist[i],v); }
}

template<int NB,int PASS>
__global__ void k_findb(const int* __restrict__ hist, int* __restrict__ ctrl){
  const int NT=NB/4;
  __shared__ int gsum[NT];
  int t=threadIdx.x;
  int s=hist[t*4]+hist[t*4+1]+hist[t*4+2]+hist[t*4+3];
  int x=s; gsum[t]=x; __syncthreads();
  for(int off=1;off<NT;off<<=1){
    int y=(t+off<NT)?gsum[t+off]:0;
    __syncthreads();
    x+=y; gsum[t]=x; __syncthreads();
  }
  int base;
  if(PASS==0) base=0; else if(PASS==1) base=ctrl[1]; else base=ctrl[3];
  int above=base+((t<NT-1)?gsum[t+1]:0);
  int incl=base+gsum[t];
  if(above<KSEL && incl>=KSEL){
    int c=above, B=0;
    for(int b=3;b>=0;b--){
      int hb=hist[t*4+b];
      if(c+hb>=KSEL){ B=t*4+b; break; }
      c+=hb;
    }
    if(PASS==0){ ctrl[0]=B; ctrl[1]=c; }
    else if(PASS==1){ ctrl[2]=(ctrl[0]<<12)|B; ctrl[3]=c; }
    else { ctrl[4]=(int)((((unsigned)ctrl[2])<<8)|(unsigned)B); ctrl[5]=KSEL-c; }
  }
}

__global__ void k_sel(const float* __restrict__ score, int* __restrict__ ctrl,
                      int* __restrict__ tie_list, unsigned char* __restrict__ sel){
  int i=blockIdx.x*256+threadIdx.x;
  if(i>=NN) return;
  unsigned b=__float_as_uint(score[i]);
  unsigned thr=(unsigned)ctrl[4];
  if(b>thr){ sel[i]=1; }
  else if(b==thr){
    sel[i]=0;
    int p=atomicAdd(&ctrl[6],1);
    if(p<4096) tie_list[p]=i;
  } else sel[i]=0;
}

__global__ __launch_bounds__(256) void k_tie(const int* __restrict__ ctrl,
    const int* __restrict__ tie_list, unsigned char* __restrict__ sel){
  int m=ctrl[6]; if(m>4096) m=4096;
  int needed=ctrl[5];
  for(int t=threadIdx.x; t<m; t+=blockDim.x){
    int idx=tie_list[t];
    int rank=0;
    for(int j=0;j<m;j++) rank+=(tie_list[j]<idx)?1:0;
    if(rank<needed) sel[idx]=1;
  }
}

// ============================================================================
extern "C" void kernel_launch(void* const* d_in, const int* in_sizes, int n_in,
                              void* d_out, int out_size, void* d_ws, size_t ws_size,
                              hipStream_t stream){
  const float* feat   =(const float*)d_in[0];
  const int*   ei     =(const int*)  d_in[2];
  const int*   src    = ei;
  const int*   dst    = ei + NE;
  const float* Wd     =(const float*)d_in[3];
  const float* bd     =(const float*)d_in[4];
  const float* prelu_a=(const float*)d_in[5];
  const float* Wbil   =(const float*)d_in[6];
  const float* bbil   =(const float*)d_in[7];
  const float* Wg1    =(const float*)d_in[8];
  const float* bg1    =(const float*)d_in[9];
  const float* Wg2    =(const float*)d_in[10];
  const float* bg2    =(const float*)d_in[11];
  const float* Wg3    =(const float*)d_in[12];
  const float* bg3    =(const float*)d_in[13];
  float* out=(float*)d_out;

  char* p=(char*)d_ws;
  auto alloc=[&](size_t bytes)->void*{ void* r=(void*)p; p+=((bytes+255)/256)*256; return r; };
  float* h_pos   =(float*)alloc((size_t)NN*DD*4);
  float* embed   =(float*)alloc((size_t)NN*DD*4);
  float* xw      =(float*)alloc((size_t)NN*DD*4);   // fp32 xw1 / bf16 xw2,xw3 / pairs (early)
  float* score   =(float*)alloc((size_t)NN*4);
  float* inv_sq  =(float*)alloc((size_t)NN*4);
  float* WbT     =(float*)alloc((size_t)DD*DD*4);
  int*   row_st  =(int*)  alloc((size_t)(NN+1)*4);
  int*   csr_src =(int*)  alloc((size_t)NE*4);
  int*   ctrl    =(int*)  alloc(64);
  int*   hist0   =(int*)  alloc(4096*4);
  int*   hist1   =(int*)  alloc(4096*4);
  int*   hist2   =(int*)  alloc(256*4);
  int*   tie_list=(int*)  alloc(4096*4);
  unsigned char* sel=(unsigned char*)alloc(NN);
  int*   btot    =(int*)  alloc((size_t)NBK*4);
  int*   boff    =(int*)  alloc((size_t)(NBK+1)*4);
  int*   blkcnt  =(int*)  alloc((size_t)NBLKA*NBK*4);
  int*   blkbase =(int*)  alloc((size_t)NBLKA*NBK*4);
  uint2* pairs   =(uint2*)xw;                       // aliased: lifetime before xw1
  ushort16* xwb  =(ushort16*)xw;
  float* fine = out;

  const int NB=(NN+255)/256;
  const int GB=(NN+127)/128;     // 391 gemm blocks
  const int AB=(NN+3)/4;         // 12500

  hipMemsetAsync(ctrl, 0, (size_t)((char*)tie_list-(char*)ctrl), stream);
  hipMemsetAsync(btot, 0, (size_t)NBK*4, stream);

  // graph structure: bucketed counting sort -> CSR + degrees + inv_sqrt
  k_bcount  <<<NBLKA,1024,0,stream>>>(dst, btot, blkcnt);
  k_bscan   <<<1,512,0,stream>>>(btot, boff, blkcnt, blkbase, row_st);
  k_bscatter<<<NBLKA,1024,0,stream>>>(src, dst, blkbase, pairs);
  k_bfinal  <<<NBK,256,0,stream>>>(pairs, boff, row_st, inv_sq, csr_src);
  k_transpose<<<64,256,0,stream>>>(Wbil, WbT);

  // h_pos = prelu(feat @ Wd + bd)
  k_gemm128<0,1,0,0><<<GB,256,0,stream>>>(feat, Wd, bd, h_pos, nullptr, prelu_a, nullptr, nullptr, nullptr);
  // embed = gcn1(h_pos)
  k_gemm128<0,0,0,0><<<GB,256,0,stream>>>(h_pos, Wg1, nullptr, xw, nullptr, nullptr, nullptr, nullptr, nullptr);
  k_agg_f32<<<AB,256,0,stream>>>(xw, row_st, csr_src, inv_sq, bg1, embed);
  // score = sigmoid(rowdot(h_pos, sigmoid(embed)@Wbil^T) + bbil)   [fused]
  k_gemm128<1,0,0,1><<<GB,256,0,stream>>>(embed, WbT, nullptr, nullptr, nullptr, nullptr, h_pos, bbil, score);
  // top-k: 3-pass LDS-privatized radix select
  k_hist<4096,0><<<64,256,0,stream>>>(score, hist0, ctrl);
  k_findb<4096,0><<<1,1024,0,stream>>>(hist0, ctrl);
  k_hist<4096,1><<<64,256,0,stream>>>(score, hist1, ctrl);
  k_findb<4096,1><<<1,1024,0,stream>>>(hist1, ctrl);
  k_hist<256,2><<<64,256,0,stream>>>(score, hist2, ctrl);
  k_findb<256,2><<<1,64,0,stream>>>(hist2, ctrl);
  k_sel<<<NB,256,0,stream>>>(score, ctrl, tie_list, sel);
  k_tie<<<1,256,0,stream>>>(ctrl, tie_list, sel);
  // fine = sel ? gcn2(embed)*score : 0   (bf16 xw2)
  k_gemm128<0,0,1,0><<<GB,256,0,stream>>>(embed, Wg2, nullptr, nullptr, xwb, nullptr, nullptr, nullptr, nullptr);
  k_agg_b16<1><<<AB,256,0,stream>>>((const uint32*)xwb, row_st, csr_src, inv_sq, bg2, fine, score, sel, nullptr);
  // out = gcn3(fine) + embed             (bf16 xw3, skip exact-zero rows)
  k_gemm128<0,0,1,0><<<GB,256,0,stream>>>(fine, Wg3, nullptr, nullptr, xwb, nullptr, nullptr, nullptr, nullptr);
  k_agg_b16<2><<<AB,256,0,stream>>>((const uint32*)xwb, row_st, csr_src, inv_sq, bg3, out, nullptr, sel, embed);
}